// Round 3
// baseline (505.428 us; speedup 1.0000x reference)
//
#include <hip/hip_runtime.h>

// Grouped node-mean pooling: in [B=32, T=512, N=21, C=256] f32 -> out [B,T,M=10,C] f32
// NODE_MAP = [[1,2],[3,4],[5,6],[7,8],[0,9],[10,11,12],[13,14],[15,16],[17,18],[19,20]]
//
// Column-per-thread layout: each thread owns one (bt, c4) column — loads all 21
// node float4s (21 independent coalesced 1KB/wave loads in flight), computes all
// 10 group means with compile-time-constant wiring (no div/mod, no constant-mem
// lookup, no branch), stores 10 float4 with non-temporal hint (output is
// write-once, never re-read).
//
// NOTE: out_size is in ELEMENTS (floats), not bytes — round-2 bug was dividing
// by bytes-per-bt (launched 1/4 of the grid, absmax 4.0 vs zero-poison).
//
// Native ext_vector_type(4) float throughout: HIP's float4 is a struct and is
// not a legal operand for __builtin_nontemporal_store.

#define N_NODES 21
#define M_GROUPS 10
#define C_CH 256
#define C4 (C_CH / 4)              // 64 float4 per (b,t,n) row == one wave per row

typedef float v4f __attribute__((ext_vector_type(4)));

__global__ __launch_bounds__(256) void pool_kernel(const v4f* __restrict__ in,
                                                   v4f* __restrict__ out,
                                                   int totalBT) {
    int idx = blockIdx.x * blockDim.x + threadIdx.x;   // (bt, c4)
    int c4  = idx & (C4 - 1);                          // C4 = 64 = wave size
    int bt  = idx >> 6;
    if (bt >= totalBT) return;

    const v4f* __restrict__ src = in + (size_t)bt * (N_NODES * C4) + c4;

    // 21 independent loads — all issued before any use (static indices -> registers).
    v4f v[N_NODES];
#pragma unroll
    for (int n = 0; n < N_NODES; ++n)
        v[n] = src[n * C4];

    v4f* __restrict__ dst = out + (size_t)bt * (M_GROUPS * C4) + c4;

    const float h  = 0.5f;
    const float t3 = (1.0f / 3.0f);

    __builtin_nontemporal_store((v[1]  + v[2])          * h,  dst + 0 * C4);
    __builtin_nontemporal_store((v[3]  + v[4])          * h,  dst + 1 * C4);
    __builtin_nontemporal_store((v[5]  + v[6])          * h,  dst + 2 * C4);
    __builtin_nontemporal_store((v[7]  + v[8])          * h,  dst + 3 * C4);
    __builtin_nontemporal_store((v[0]  + v[9])          * h,  dst + 4 * C4);
    __builtin_nontemporal_store((v[10] + v[11] + v[12]) * t3, dst + 5 * C4);
    __builtin_nontemporal_store((v[13] + v[14])         * h,  dst + 6 * C4);
    __builtin_nontemporal_store((v[15] + v[16])         * h,  dst + 7 * C4);
    __builtin_nontemporal_store((v[17] + v[18])         * h,  dst + 8 * C4);
    __builtin_nontemporal_store((v[19] + v[20])         * h,  dst + 9 * C4);
}

extern "C" void kernel_launch(void* const* d_in, const int* in_sizes, int n_in,
                              void* d_out, int out_size, void* d_ws, size_t ws_size,
                              hipStream_t stream) {
    const v4f* in  = (const v4f*)d_in[0];
    v4f*       out = (v4f*)d_out;

    int totalBT = out_size / (M_GROUPS * C_CH);        // out_size in floats -> 32*512 = 16384
    int total   = totalBT * C4;                        // 1,048,576 threads
    int block   = 256;
    int grid    = (total + block - 1) / block;         // 4096 blocks

    pool_kernel<<<grid, block, 0, stream>>>(in, out, totalBT);
}

// Round 4
// 493.389 us; speedup vs baseline: 1.0244x; 1.0244x over previous
//
#include <hip/hip_runtime.h>

// Grouped node-mean pooling: in [B=32, T=512, N=21, C=256] f32 -> out [B,T,M=10,C] f32
// NODE_MAP = [[1,2],[3,4],[5,6],[7,8],[0,9],[10,11,12],[13,14],[15,16],[17,18],[19,20]]
//
// Thread-per-output-float4 (REVERT to proven-best 492.4/493.2 µs structure).
// Each 64-lane wave covers exactly one (bt, m) row (C4 = 64), so:
//  - the group-table constant loads are wave-uniform (scalar broadcast, free)
//  - the n2>=0 branch is wave-uniform (no divergence)
//  - 2-3 x 1KB coalesced loads + 1KB coalesced store per wave
// Input is read exactly once (groups partition the 21 nodes) -> 520 MB minimal
// traffic, BW-floor bound. Round-3 experiment (column-per-thread + NT stores)
// regressed 493->505: NT stores / VGPR pressure hurt a pure streaming kernel.

#define N_NODES 21
#define M_GROUPS 10
#define C_CH 256
#define C4 (C_CH / 4)              // 64 float4 per (b,t,n) row

__device__ __constant__ int   g_n0[M_GROUPS]    = { 1, 3, 5, 7, 0, 10, 13, 15, 17, 19};
__device__ __constant__ int   g_n1[M_GROUPS]    = { 2, 4, 6, 8, 9, 11, 14, 16, 18, 20};
__device__ __constant__ int   g_n2[M_GROUPS]    = {-1,-1,-1,-1,-1, 12, -1, -1, -1, -1};
__device__ __constant__ float g_scale[M_GROUPS] = {0.5f, 0.5f, 0.5f, 0.5f, 0.5f,
                                                   (1.0f/3.0f), 0.5f, 0.5f, 0.5f, 0.5f};

__global__ __launch_bounds__(256) void pool_kernel(const float4* __restrict__ in,
                                                   float4* __restrict__ out,
                                                   int total4) {
    int idx = blockIdx.x * blockDim.x + threadIdx.x;
    if (idx >= total4) return;

    // out float4 layout: idx = bt * (M_GROUPS*C4) + m * C4 + c4
    int c4 = idx & (C4 - 1);               // C4 = 64, power of two
    int t  = idx >> 6;                     // bt * 10 + m
    int m  = t % M_GROUPS;
    int bt = t / M_GROUPS;

    // input float4 base for this (b,t): bt * N_NODES * C4
    int base = bt * (N_NODES * C4) + c4;

    int n0 = g_n0[m];
    int n1 = g_n1[m];
    int n2 = g_n2[m];
    float s = g_scale[m];

    float4 a = in[base + n0 * C4];
    float4 b = in[base + n1 * C4];

    float4 r;
    r.x = a.x + b.x;
    r.y = a.y + b.y;
    r.z = a.z + b.z;
    r.w = a.w + b.w;

    if (n2 >= 0) {
        float4 c = in[base + n2 * C4];
        r.x += c.x; r.y += c.y; r.z += c.z; r.w += c.w;
    }

    r.x *= s; r.y *= s; r.z *= s; r.w *= s;
    out[idx] = r;
}

extern "C" void kernel_launch(void* const* d_in, const int* in_sizes, int n_in,
                              void* d_out, int out_size, void* d_ws, size_t ws_size,
                              hipStream_t stream) {
    const float4* in  = (const float4*)d_in[0];
    float4*       out = (float4*)d_out;

    int total4 = out_size / 4;             // 32*512*10*256/4 = 10,485,760
    int block  = 256;
    int grid   = (total4 + block - 1) / block;

    pool_kernel<<<grid, block, 0, stream>>>(in, out, total4);
}